// Round 12
// baseline (636.158 us; speedup 1.0000x reference)
//
#include <hip/hip_runtime.h>
#include <hip/hip_bf16.h>

#define N_NODES 100000
#define N_EDGES 1600000
#define IN_DIM 128
#define HID 256
#define NUM_GRAPHS 2048
#define M_PAD 100096  // 782 * 128
#define SCAN_BLOCKS 98  // ceil(100000/1024)
#define X2BF_BLOCKS 12500  // N_NODES*IN_DIM/4/256
#define FILL_BLOCKS 784
#define FILL_STRIDE (FILL_BLOCKS * 256)   // 200704
#define FILL_EPT 8                        // edges per thread (784*256*8 >= 1.6M)
#define FILL_PASSES 25                    // buckets of 4096 dst nodes
#define POOL_GSPAN 16                     // graphs per LDS pooling window

typedef __bf16 bf16x8 __attribute__((ext_vector_type(8)));
typedef float f32x4 __attribute__((ext_vector_type(4)));

typedef const void __attribute__((address_space(1))) gvoid_t;
typedef void __attribute__((address_space(3))) svoid_t;

__device__ inline unsigned short f2bf(float x) {
    union { __hip_bfloat16 h; unsigned short u; } v;
    v.h = __float2bfloat16(x);
    return v.u;
}
__device__ inline float bf2f(unsigned short u) {
    return __uint_as_float(((unsigned int)u) << 16);
}
__device__ inline int rfl(int x) { return __builtin_amdgcn_readfirstlane(x); }

// ---------------- degree histogram over dst + per-edge ordinal ----------------
__global__ void count_deg_kernel(const int* __restrict__ ei, int* __restrict__ deg,
                                 int* __restrict__ eord) {
    int e = blockIdx.x * blockDim.x + threadIdx.x;
    if (e < N_EDGES) {
        eord[e] = atomicAdd(&deg[ei[N_EDGES + e]], 1);
    }
}

// ---------------- block sums (+ fused dinv) ----------------
__global__ __launch_bounds__(1024) void blocksum_kernel(const int* __restrict__ deg,
                                                        int* __restrict__ bsum,
                                                        float* __restrict__ dinv) {
    int i = blockIdx.x * 1024 + threadIdx.x;
    int v = (i < N_NODES) ? deg[i] : 0;
    if (i < N_NODES) dinv[i] = rsqrtf((float)(v + 1));  // self-loop adds 1
    __shared__ int s[1024];
    int t = threadIdx.x;
    s[t] = v;
    __syncthreads();
#pragma unroll
    for (int off = 512; off > 0; off >>= 1) {
        if (t < off) s[t] += s[t + off];
        __syncthreads();
    }
    if (t == 0) bsum[blockIdx.x] = s[0];
}

// ---------------- scanout with inlined block-sum scan -----------------------
__global__ __launch_bounds__(1024) void scanout_kernel(const int* __restrict__ deg,
                                                       const int* __restrict__ bsum,
                                                       int* __restrict__ rowptr) {
    int t = threadIdx.x;
    __shared__ int bs[128];
    if (t < 128) bs[t] = (t < SCAN_BLOCKS) ? bsum[t] : 0;
    __syncthreads();
#pragma unroll
    for (int off = 1; off < 128; off <<= 1) {
        int x = 0;
        if (t < 128 && t >= off) x = bs[t - off];
        __syncthreads();
        if (t < 128) bs[t] += x;
        __syncthreads();
    }
    int base = (blockIdx.x > 0) ? bs[blockIdx.x - 1] : 0;

    int i = blockIdx.x * 1024 + t;
    int v = (i < N_NODES) ? deg[i] : 0;
    __shared__ int s[1024];
    s[t] = v;
    __syncthreads();
#pragma unroll
    for (int off = 1; off < 1024; off <<= 1) {
        int x = (t >= off) ? s[t - off] : 0;
        __syncthreads();
        s[t] += x;
        __syncthreads();
    }
    int excl = (t > 0) ? s[t - 1] : 0;
    if (i < N_NODES) rowptr[i] = base + excl;
    if (i == N_NODES - 1) rowptr[N_NODES] = base + s[t];
}

// ---------------- bucket fill: register-resident multi-pass ----------------
__global__ __launch_bounds__(256) void fill_kernel(const int* __restrict__ ei,
                                                   const int* __restrict__ rowptr,
                                                   const int* __restrict__ eord,
                                                   int* __restrict__ esrc) {
    int base = blockIdx.x * 256 + threadIdx.x;
    int src[FILL_EPT], pos[FILL_EPT], bkt[FILL_EPT];
#pragma unroll
    for (int i = 0; i < FILL_EPT; i++) {
        int e = base + i * FILL_STRIDE;
        if (e < N_EDGES) {
            int d = ei[N_EDGES + e];
            src[i] = ei[e];
            pos[i] = rowptr[d] + eord[e];
            bkt[i] = d >> 12;
        } else {
            bkt[i] = -1;
        }
    }
    for (int p = 0; p < FILL_PASSES; p++) {
#pragma unroll
        for (int i = 0; i < FILL_EPT; i++) {
            if (bkt[i] == p) esrc[pos[i]] = src[i];
        }
    }
}

// ---------------- merged prep: x->bf16 prescaled  +  weight transpose/split ----
__global__ void prep_kernel(const float* __restrict__ x, const float* __restrict__ dinv,
                            unsigned short* __restrict__ xb,
                            const float* __restrict__ W1, const float* __restrict__ W2,
                            unsigned short* __restrict__ W1th, unsigned short* __restrict__ W1tl,
                            unsigned short* __restrict__ W2th, unsigned short* __restrict__ W2tl) {
    int b = blockIdx.x;
    if (b < X2BF_BLOCKS) {
        size_t i = ((size_t)b * 256 + threadIdx.x) * 4;
        int node = (int)(i >> 7);  // 128 floats per row
        float dv = dinv[node];
        float4 v = *(const float4*)(x + i);
        ushort4 o;
        o.x = f2bf(v.x * dv); o.y = f2bf(v.y * dv);
        o.z = f2bf(v.z * dv); o.w = f2bf(v.w * dv);
        *(ushort4*)(xb + i) = o;
    } else {
        int idx = (b - X2BF_BLOCKS) * 256 + threadIdx.x;
        if (idx < IN_DIM * 256) {
            int k = idx >> 8, n = idx & 255;
            float w = W1[idx];
            unsigned short h = f2bf(w);
            unsigned short l = f2bf(w - bf2f(h));
            W1th[n * IN_DIM + k] = h;
            W1tl[n * IN_DIM + k] = l;
        } else {
            int i2 = idx - IN_DIM * 256;
            int k = i2 >> 8, n = i2 & 255;
            float w = W2[i2];
            unsigned short h = f2bf(w);
            unsigned short l = f2bf(w - bf2f(h));
            W2th[n * HID + k] = h;
            W2tl[n * HID + k] = l;
        }
    }
}

// ---------------- gather agg 128-dim from prescaled bf16, hi/lo out ----------
__global__ __launch_bounds__(256) void agg128_kernel(const unsigned short* __restrict__ X,
                                                     const int* __restrict__ esrc,
                                                     const int* __restrict__ rowptr,
                                                     const float* __restrict__ dinv,
                                                     unsigned short* __restrict__ Ah,
                                                     unsigned short* __restrict__ Al) {
    int node = rfl(blockIdx.x * 4 + (threadIdx.x >> 6));
    int lane = threadIdx.x & 63;
    float ddst = dinv[node];
    int s = rfl(rowptr[node]);
    int e = rfl(rowptr[node + 1]);

    ushort2 h0 = *((const ushort2*)(X + (size_t)node * 128) + lane);
    float2 acc = make_float2(bf2f(h0.x), bf2f(h0.y));

    int j = s;
    for (; j + 8 <= e; j += 8) {
        int si[8];
#pragma unroll
        for (int u = 0; u < 8; u++) si[u] = rfl(esrc[j + u]);
        ushort2 xv[8];
#pragma unroll
        for (int u = 0; u < 8; u++)
            xv[u] = *((const ushort2*)(X + (size_t)si[u] * 128) + lane);
#pragma unroll
        for (int u = 0; u < 8; u++) {
            acc.x += bf2f(xv[u].x);
            acc.y += bf2f(xv[u].y);
        }
    }
    for (; j + 4 <= e; j += 4) {
        int si[4];
#pragma unroll
        for (int u = 0; u < 4; u++) si[u] = rfl(esrc[j + u]);
        ushort2 xv[4];
#pragma unroll
        for (int u = 0; u < 4; u++)
            xv[u] = *((const ushort2*)(X + (size_t)si[u] * 128) + lane);
#pragma unroll
        for (int u = 0; u < 4; u++) {
            acc.x += bf2f(xv[u].x);
            acc.y += bf2f(xv[u].y);
        }
    }
    for (; j < e; j++) {
        int src = rfl(esrc[j]);
        ushort2 xv = *((const ushort2*)(X + (size_t)src * 128) + lane);
        acc.x += bf2f(xv.x);
        acc.y += bf2f(xv.y);
    }
    acc.x *= ddst;
    acc.y *= ddst;
    size_t o = (size_t)node * 128 + lane * 2;
    ushort2 hi, lo;
    hi.x = f2bf(acc.x); lo.x = f2bf(acc.x - bf2f(hi.x));
    hi.y = f2bf(acc.y); lo.y = f2bf(acc.y - bf2f(hi.y));
    *(ushort2*)(Ah + o) = hi;
    *(ushort2*)(Al + o) = lo;
}

// ---------------- gather agg 256-dim from prescaled bf16, hi out ----------
__global__ __launch_bounds__(256) void agg256_kernel(const unsigned short* __restrict__ H,
                                                     const int* __restrict__ esrc,
                                                     const int* __restrict__ rowptr,
                                                     const float* __restrict__ dinv,
                                                     unsigned short* __restrict__ Ah) {
    int node = rfl(blockIdx.x * 4 + (threadIdx.x >> 6));
    int lane = threadIdx.x & 63;
    float ddst = dinv[node];
    int s = rfl(rowptr[node]);
    int e = rfl(rowptr[node + 1]);

    ushort4 h0 = *((const ushort4*)(H + (size_t)node * 256) + lane);
    float4 acc = make_float4(bf2f(h0.x), bf2f(h0.y), bf2f(h0.z), bf2f(h0.w));

    int j = s;
    for (; j + 8 <= e; j += 8) {
        int si[8];
#pragma unroll
        for (int u = 0; u < 8; u++) si[u] = rfl(esrc[j + u]);
        ushort4 xv[8];
#pragma unroll
        for (int u = 0; u < 8; u++)
            xv[u] = *((const ushort4*)(H + (size_t)si[u] * 256) + lane);
#pragma unroll
        for (int u = 0; u < 8; u++) {
            acc.x += bf2f(xv[u].x);
            acc.y += bf2f(xv[u].y);
            acc.z += bf2f(xv[u].z);
            acc.w += bf2f(xv[u].w);
        }
    }
    for (; j + 4 <= e; j += 4) {
        int si[4];
#pragma unroll
        for (int u = 0; u < 4; u++) si[u] = rfl(esrc[j + u]);
        ushort4 xv[4];
#pragma unroll
        for (int u = 0; u < 4; u++)
            xv[u] = *((const ushort4*)(H + (size_t)si[u] * 256) + lane);
#pragma unroll
        for (int u = 0; u < 4; u++) {
            acc.x += bf2f(xv[u].x);
            acc.y += bf2f(xv[u].y);
            acc.z += bf2f(xv[u].z);
            acc.w += bf2f(xv[u].w);
        }
    }
    for (; j < e; j++) {
        int src = rfl(esrc[j]);
        ushort4 xv = *((const ushort4*)(H + (size_t)src * 256) + lane);
        acc.x += bf2f(xv.x);
        acc.y += bf2f(xv.y);
        acc.z += bf2f(xv.z);
        acc.w += bf2f(xv.w);
    }
    acc.x *= ddst; acc.y *= ddst; acc.z *= ddst; acc.w *= ddst;
    size_t o = (size_t)node * 256 + lane * 4;
    ushort4 hi;
    hi.x = f2bf(acc.x); hi.y = f2bf(acc.y);
    hi.z = f2bf(acc.z); hi.w = f2bf(acc.w);
    *(ushort4*)(Ah + o) = hi;
}

// ---------------- MFMA GEMM: relu(A @ W + b) -> bf16 out OR fused mean-pool ----
// ASPLIT: A hi+lo (3-term) else hi only (2-term). SCALEOUT: row-scale output.
// POOL: skip the C write; reduce relu values into poolsum[graph][col] via an
// LDS [16][128] window + global f32 atomics. Eliminates H2 write + pool re-read.
// launch_bounds(256,2): r11's (256,3) squeezed arch-VGPRs to 76 -> k-loop
// serialized on fragment loads (179us, all pipes idle). 2 blocks/CU is the
// verified sweet spot for this k-loop.
template <int K, bool ASPLIT, bool SCALEOUT, bool POOL>
__launch_bounds__(256, 2)
__global__ void mfma_gemm_bias_relu(const unsigned short* __restrict__ Ah,
                                    const unsigned short* __restrict__ Al,
                                    const unsigned short* __restrict__ Bh,
                                    const unsigned short* __restrict__ Bl,
                                    const float* __restrict__ bias,
                                    const float* __restrict__ dscale,
                                    const int* __restrict__ batch,
                                    float* __restrict__ poolsum,
                                    unsigned short* __restrict__ Cout) {
    constexpr int NT = ASPLIT ? 4 : 3;
    __shared__ __align__(16) unsigned short lds[NT * 128 * 32];
    unsigned short* Ahs = lds;
    unsigned short* Als = lds + 4096;                    // only valid if ASPLIT
    unsigned short* Bhs = lds + (ASPLIT ? 8192 : 4096);
    unsigned short* Bls = lds + (ASPLIT ? 12288 : 8192);
    __shared__ int sbatch[128];

    int tid = threadIdx.x;
    int bm = (blockIdx.y * 8 + (blockIdx.x & 7)) * 128;
    int bn = (blockIdx.x >> 3) * 128;
    int wid = tid >> 6, lane = tid & 63;
    int wm = wid & 1, wn = wid >> 1;
    int lrow = lane & 15, quad = lane >> 4;

    if (POOL && tid < 128) {
        int row = bm + tid;
        sbatch[tid] = (row < N_NODES) ? batch[row] : -1;
    }

    f32x4 acc[4][4];
#pragma unroll
    for (int mi = 0; mi < 4; mi++)
#pragma unroll
        for (int ni = 0; ni < 4; ni++) acc[mi][ni] = (f32x4){0.f, 0.f, 0.f, 0.f};

    for (int k0 = 0; k0 < K; k0 += 32) {
#pragma unroll
        for (int i = 0; i < NT * 2; i++) {
            int c = tid + 256 * i;
            int tile = c >> 9;
            int w = c & 511;
            int row = w >> 2;
            int part = w & 3;
            const unsigned short* g;
            if (ASPLIT) {
                if (tile == 0)      g = Ah + (size_t)(bm + row) * K + k0 + part * 8;
                else if (tile == 1) g = Al + (size_t)(bm + row) * K + k0 + part * 8;
                else if (tile == 2) g = Bh + (size_t)(bn + row) * K + k0 + part * 8;
                else                g = Bl + (size_t)(bn + row) * K + k0 + part * 8;
            } else {
                if (tile == 0)      g = Ah + (size_t)(bm + row) * K + k0 + part * 8;
                else if (tile == 1) g = Bh + (size_t)(bn + row) * K + k0 + part * 8;
                else                g = Bl + (size_t)(bn + row) * K + k0 + part * 8;
            }
            __builtin_amdgcn_global_load_lds(
                (gvoid_t*)g,
                (svoid_t*)((char*)lds + (size_t)c * 16),
                16, 0, 0);
        }
        __syncthreads();

        bf16x8 ah[4], al[4], bh[4], bl[4];
#pragma unroll
        for (int mi = 0; mi < 4; mi++) {
            int r = wm * 64 + mi * 16 + lrow;
            ah[mi] = *(const bf16x8*)&Ahs[r * 32 + quad * 8];
            if (ASPLIT) al[mi] = *(const bf16x8*)&Als[r * 32 + quad * 8];
        }
#pragma unroll
        for (int ni = 0; ni < 4; ni++) {
            int r = wn * 64 + ni * 16 + lrow;
            bh[ni] = *(const bf16x8*)&Bhs[r * 32 + quad * 8];
            bl[ni] = *(const bf16x8*)&Bls[r * 32 + quad * 8];
        }
#pragma unroll
        for (int mi = 0; mi < 4; mi++)
#pragma unroll
            for (int ni = 0; ni < 4; ni++) {
                acc[mi][ni] = __builtin_amdgcn_mfma_f32_16x16x32_bf16(ah[mi], bh[ni], acc[mi][ni], 0, 0, 0);
                acc[mi][ni] = __builtin_amdgcn_mfma_f32_16x16x32_bf16(ah[mi], bl[ni], acc[mi][ni], 0, 0, 0);
                if (ASPLIT)
                    acc[mi][ni] = __builtin_amdgcn_mfma_f32_16x16x32_bf16(al[mi], bh[ni], acc[mi][ni], 0, 0, 0);
            }
        __syncthreads();
    }

    float bv[4];
#pragma unroll
    for (int ni = 0; ni < 4; ni++) bv[ni] = bias[bn + wn * 64 + ni * 16 + lrow];

    if (POOL) {
        // ---- fused mean-pool epilogue (staging LDS is dead; reuse as [16][128]) ----
        if (bm >= N_NODES) return;
        float* pool_lds = (float*)lds;
        int lv = (N_NODES - 1 - bm < 127) ? (N_NODES - 1 - bm) : 127;
        int gmin = sbatch[0];
        int gmax = sbatch[lv];
        for (int gbase = gmin; gbase <= gmax; gbase += POOL_GSPAN) {
            for (int s = tid; s < POOL_GSPAN * 128; s += 256) pool_lds[s] = 0.f;
            __syncthreads();
#pragma unroll
            for (int mi = 0; mi < 4; mi++) {
                int row0 = bm + wm * 64 + mi * 16 + quad * 4;
#pragma unroll
                for (int rr = 0; rr < 4; rr++) {
                    int row = row0 + rr;
                    if (row < N_NODES) {
                        int g = sbatch[row - bm];
                        int gi = g - gbase;
                        if (gi >= 0 && gi < POOL_GSPAN) {
#pragma unroll
                            for (int ni = 0; ni < 4; ni++) {
                                int colp = wn * 64 + ni * 16 + lrow;
                                float v = fmaxf(acc[mi][ni][rr] + bv[ni], 0.f);
                                atomicAdd(&pool_lds[gi * 128 + colp], v);
                            }
                        }
                    }
                }
            }
            __syncthreads();
            for (int s = tid; s < POOL_GSPAN * 128; s += 256) {
                int gi = s >> 7, c = s & 127;
                float v = pool_lds[s];
                if (gbase + gi <= gmax && v != 0.f)
                    atomicAdd(&poolsum[(size_t)(gbase + gi) * 256 + bn + c], v);
            }
            __syncthreads();
        }
        return;
    }

    // ---- standard epilogue: bias + relu (+ row scale) + bf16 store ----
#pragma unroll
    for (int mi = 0; mi < 4; mi++) {
        int row0 = bm + wm * 64 + mi * 16 + quad * 4;
        float dsc[4];
        if (SCALEOUT) {
#pragma unroll
            for (int r = 0; r < 4; r++)
                dsc[r] = (row0 + r < N_NODES) ? dscale[row0 + r] : 0.f;
        }
#pragma unroll
        for (int ni = 0; ni < 4; ni++) {
            int col = bn + wn * 64 + ni * 16 + lrow;
#pragma unroll
            for (int r = 0; r < 4; r++) {
                int row = row0 + r;
                if (row < N_NODES) {
                    float v = fmaxf(acc[mi][ni][r] + bv[ni], 0.f);
                    if (SCALEOUT) v *= dsc[r];
                    Cout[(size_t)row * 256 + col] = f2bf(v);
                }
            }
        }
    }
}

// ---------------- MLP head on pooled sums ----------
__global__ __launch_bounds__(256) void mlp_kernel(const float* __restrict__ poolsum,
                                                  const int* __restrict__ batch,
                                                  const float* __restrict__ Wf1,
                                                  const float* __restrict__ bf1,
                                                  const float* __restrict__ Wf2,
                                                  const float* __restrict__ bf2,
                                                  float* __restrict__ out) {
    int g = blockIdx.x;
    int t = threadIdx.x;  // 0..255
    __shared__ int bounds[2];
    if (t < 2) {
        int target = g + t;
        int lo = 0, hi = N_NODES;
        while (lo < hi) {
            int mid = (lo + hi) >> 1;
            if (batch[mid] < target) lo = mid + 1;
            else hi = mid;
        }
        bounds[t] = lo;
    }
    __syncthreads();
    int lo = bounds[0], hi = bounds[1];
    float inv = (hi > lo) ? 1.0f / (float)(hi - lo) : 0.f;

    __shared__ float p[256];
    p[t] = poolsum[(size_t)g * 256 + t] * inv;
    __syncthreads();

    float hv = 0.f;
    if (t < 128) {
        float a = bf1[t];
#pragma unroll 8
        for (int k = 0; k < 256; k++) a = fmaf(p[k], Wf1[k * 128 + t], a);
        hv = fmaxf(a, 0.f) * Wf2[t];
    }
#pragma unroll
    for (int off = 32; off > 0; off >>= 1) hv += __shfl_down(hv, off, 64);
    __shared__ float partial[4];
    if ((t & 63) == 0) partial[t >> 6] = hv;
    __syncthreads();
    if (t == 0) out[g] = partial[0] + partial[1] + bf2[0];
}

extern "C" void kernel_launch(void* const* d_in, const int* in_sizes, int n_in,
                              void* d_out, int out_size, void* d_ws, size_t ws_size,
                              hipStream_t stream) {
    const float* x   = (const float*)d_in[0];
    const int*   ei  = (const int*)d_in[1];
    const int*   bat = (const int*)d_in[2];
    const float* W1  = (const float*)d_in[3];
    const float* b1  = (const float*)d_in[4];
    const float* W2  = (const float*)d_in[5];
    const float* b2  = (const float*)d_in[6];
    const float* Wf1 = (const float*)d_in[7];
    const float* bf1 = (const float*)d_in[8];
    const float* Wf2 = (const float*)d_in[9];
    const float* bf2 = (const float*)d_in[10];
    float* out = (float*)d_out;

    char* ws = (char*)d_ws;
    // layout (peak end 0x9B20000 = 162.5 MB):
    //   0x0000000 deg        0x0080000 dinv      0x0100000 rowptr
    //   0x01F0000 bsum
    //   0x0200000 esrc (6.4 MB)
    //   0x0820000 W1th  0x0830000 W1tl  0x0840000 W2th  0x0860000 W2tl
    //   0x0880000 A1h (25.6 MB) / later A2 (51.2 MB, single; ends 0x3960000)
    //   0x20F0000 eord (6.4 MB, dead after fill) -> A1l (25.6 MB)  [A2 overlaps]
    //   0x4000000 poolsum (2 MB, in the hole 0x3960000..0x6A40000)
    //   0x6A40000 xbf (25.6 MB) -> H1bf (51.2 MB) time-multiplexed (no H2 anymore)
    int*   deg    = (int*)(ws);
    float* dinv   = (float*)(ws + 0x0080000);
    int*   rowptr = (int*)(ws + 0x0100000);
    int*   bsum   = (int*)(ws + 0x01F0000);
    int*   esrc   = (int*)(ws + 0x0200000);
    unsigned short* W1th = (unsigned short*)(ws + 0x0820000);
    unsigned short* W1tl = (unsigned short*)(ws + 0x0830000);
    unsigned short* W2th = (unsigned short*)(ws + 0x0840000);
    unsigned short* W2tl = (unsigned short*)(ws + 0x0860000);
    unsigned short* A1h  = (unsigned short*)(ws + 0x0880000);
    int*   eord   = (int*)(ws + 0x20F0000);                    // dead before A1l written
    unsigned short* A1l  = (unsigned short*)(ws + 0x20F0000);
    unsigned short* A2   = (unsigned short*)(ws + 0x0880000);  // reuses A1h+A1l space
    float* poolsum = (float*)(ws + 0x4000000);
    unsigned short* xbf  = (unsigned short*)(ws + 0x6A40000);
    unsigned short* H1bf = (unsigned short*)(ws + 0x6A40000);  // overwrites dead xbf
    (void)ws_size;

    hipMemsetAsync(deg, 0, (size_t)N_NODES * sizeof(int), stream);
    hipMemsetAsync(poolsum, 0, (size_t)NUM_GRAPHS * HID * sizeof(float), stream);

    // CSR build front half (produces dinv needed by the prescaled prep)
    count_deg_kernel<<<(N_EDGES + 255) / 256, 256, 0, stream>>>(ei, deg, eord);
    blocksum_kernel<<<SCAN_BLOCKS, 1024, 0, stream>>>(deg, bsum, dinv);

    // merged prep (x prescale+cast, weight transpose+split)
    prep_kernel<<<X2BF_BLOCKS + 384, 256, 0, stream>>>(x, dinv, xbf, W1, W2,
                                                       W1th, W1tl, W2th, W2tl);

    // CSR build back half
    scanout_kernel<<<SCAN_BLOCKS, 1024, 0, stream>>>(deg, bsum, rowptr);
    fill_kernel<<<FILL_BLOCKS, 256, 0, stream>>>(ei, rowptr, eord, esrc);

    // layer 1: A1 = split(ddst * sum X'); H1' = dinv * relu(A1 @ W1 + b1)  [3-term]
    agg128_kernel<<<N_NODES / 4, 256, 0, stream>>>(xbf, esrc, rowptr, dinv, A1h, A1l);
    {
        dim3 grid(16, 98);
        mfma_gemm_bias_relu<IN_DIM, true, true, false><<<grid, 256, 0, stream>>>(
            A1h, A1l, W1th, W1tl, b1, dinv, nullptr, nullptr, H1bf);
    }

    // layer 2: A2 = bf16(ddst * sum H1'); poolsum += relu(A2 @ W2 + b2) per graph
    agg256_kernel<<<N_NODES / 4, 256, 0, stream>>>(H1bf, esrc, rowptr, dinv, A2);
    {
        dim3 grid(16, 98);
        mfma_gemm_bias_relu<HID, false, false, true><<<grid, 256, 0, stream>>>(
            A2, nullptr, W2th, W2tl, b2, nullptr, bat, poolsum, nullptr);
    }

    // MLP head on pooled sums
    mlp_kernel<<<NUM_GRAPHS, 256, 0, stream>>>(poolsum, bat, Wf1, bf1, Wf2, bf2, out);
}

// Round 13
// 516.131 us; speedup vs baseline: 1.2326x; 1.2326x over previous
//
#include <hip/hip_runtime.h>
#include <hip/hip_bf16.h>

#define N_NODES 100000
#define N_EDGES 1600000
#define IN_DIM 128
#define HID 256
#define NUM_GRAPHS 2048
#define M_PAD 100096  // 782 * 128
#define SCAN_BLOCKS 98  // ceil(100000/1024)
#define X2BF_BLOCKS 12500  // N_NODES*IN_DIM/4/256
#define FILL_BLOCKS 784
#define FILL_STRIDE (FILL_BLOCKS * 256)   // 200704
#define FILL_EPT 8                        // edges per thread (784*256*8 >= 1.6M)
#define FILL_PASSES 25                    // buckets of 4096 dst nodes

typedef __bf16 bf16x8 __attribute__((ext_vector_type(8)));
typedef float f32x4 __attribute__((ext_vector_type(4)));

typedef const void __attribute__((address_space(1))) gvoid_t;
typedef void __attribute__((address_space(3))) svoid_t;

__device__ inline unsigned short f2bf(float x) {
    union { __hip_bfloat16 h; unsigned short u; } v;
    v.h = __float2bfloat16(x);
    return v.u;
}
__device__ inline float bf2f(unsigned short u) {
    return __uint_as_float(((unsigned int)u) << 16);
}
__device__ inline int rfl(int x) { return __builtin_amdgcn_readfirstlane(x); }

// ---------------- degree histogram over dst + per-edge ordinal ----------------
__global__ void count_deg_kernel(const int* __restrict__ ei, int* __restrict__ deg,
                                 int* __restrict__ eord) {
    int e = blockIdx.x * blockDim.x + threadIdx.x;
    if (e < N_EDGES) {
        eord[e] = atomicAdd(&deg[ei[N_EDGES + e]], 1);
    }
}

// ---------------- block sums (+ fused dinv) ----------------
__global__ __launch_bounds__(1024) void blocksum_kernel(const int* __restrict__ deg,
                                                        int* __restrict__ bsum,
                                                        float* __restrict__ dinv) {
    int i = blockIdx.x * 1024 + threadIdx.x;
    int v = (i < N_NODES) ? deg[i] : 0;
    if (i < N_NODES) dinv[i] = rsqrtf((float)(v + 1));  // self-loop adds 1
    __shared__ int s[1024];
    int t = threadIdx.x;
    s[t] = v;
    __syncthreads();
#pragma unroll
    for (int off = 512; off > 0; off >>= 1) {
        if (t < off) s[t] += s[t + off];
        __syncthreads();
    }
    if (t == 0) bsum[blockIdx.x] = s[0];
}

// ---------------- scanout with inlined block-sum scan -----------------------
__global__ __launch_bounds__(1024) void scanout_kernel(const int* __restrict__ deg,
                                                       const int* __restrict__ bsum,
                                                       int* __restrict__ rowptr) {
    int t = threadIdx.x;
    __shared__ int bs[128];
    if (t < 128) bs[t] = (t < SCAN_BLOCKS) ? bsum[t] : 0;
    __syncthreads();
#pragma unroll
    for (int off = 1; off < 128; off <<= 1) {
        int x = 0;
        if (t < 128 && t >= off) x = bs[t - off];
        __syncthreads();
        if (t < 128) bs[t] += x;
        __syncthreads();
    }
    int base = (blockIdx.x > 0) ? bs[blockIdx.x - 1] : 0;

    int i = blockIdx.x * 1024 + t;
    int v = (i < N_NODES) ? deg[i] : 0;
    __shared__ int s[1024];
    s[t] = v;
    __syncthreads();
#pragma unroll
    for (int off = 1; off < 1024; off <<= 1) {
        int x = (t >= off) ? s[t - off] : 0;
        __syncthreads();
        s[t] += x;
        __syncthreads();
    }
    int excl = (t > 0) ? s[t - 1] : 0;
    if (i < N_NODES) rowptr[i] = base + excl;
    if (i == N_NODES - 1) rowptr[N_NODES] = base + s[t];
}

// ---------------- bucket fill: register-resident multi-pass ----------------
__global__ __launch_bounds__(256) void fill_kernel(const int* __restrict__ ei,
                                                   const int* __restrict__ rowptr,
                                                   const int* __restrict__ eord,
                                                   int* __restrict__ esrc) {
    int base = blockIdx.x * 256 + threadIdx.x;
    int src[FILL_EPT], pos[FILL_EPT], bkt[FILL_EPT];
#pragma unroll
    for (int i = 0; i < FILL_EPT; i++) {
        int e = base + i * FILL_STRIDE;
        if (e < N_EDGES) {
            int d = ei[N_EDGES + e];
            src[i] = ei[e];
            pos[i] = rowptr[d] + eord[e];
            bkt[i] = d >> 12;
        } else {
            bkt[i] = -1;
        }
    }
    for (int p = 0; p < FILL_PASSES; p++) {
#pragma unroll
        for (int i = 0; i < FILL_EPT; i++) {
            if (bkt[i] == p) esrc[pos[i]] = src[i];
        }
    }
}

// ---------------- merged prep: x->bf16 prescaled  +  weight transpose/split ----
__global__ void prep_kernel(const float* __restrict__ x, const float* __restrict__ dinv,
                            unsigned short* __restrict__ xb,
                            const float* __restrict__ W1, const float* __restrict__ W2,
                            unsigned short* __restrict__ W1th, unsigned short* __restrict__ W1tl,
                            unsigned short* __restrict__ W2th, unsigned short* __restrict__ W2tl) {
    int b = blockIdx.x;
    if (b < X2BF_BLOCKS) {
        size_t i = ((size_t)b * 256 + threadIdx.x) * 4;
        int node = (int)(i >> 7);  // 128 floats per row
        float dv = dinv[node];
        float4 v = *(const float4*)(x + i);
        ushort4 o;
        o.x = f2bf(v.x * dv); o.y = f2bf(v.y * dv);
        o.z = f2bf(v.z * dv); o.w = f2bf(v.w * dv);
        *(ushort4*)(xb + i) = o;
    } else {
        int idx = (b - X2BF_BLOCKS) * 256 + threadIdx.x;
        if (idx < IN_DIM * 256) {
            int k = idx >> 8, n = idx & 255;
            float w = W1[idx];
            unsigned short h = f2bf(w);
            unsigned short l = f2bf(w - bf2f(h));
            W1th[n * IN_DIM + k] = h;
            W1tl[n * IN_DIM + k] = l;
        } else {
            int i2 = idx - IN_DIM * 256;
            int k = i2 >> 8, n = i2 & 255;
            float w = W2[i2];
            unsigned short h = f2bf(w);
            unsigned short l = f2bf(w - bf2f(h));
            W2th[n * HID + k] = h;
            W2tl[n * HID + k] = l;
        }
    }
}

// ---------------- gather agg 128-dim from prescaled bf16, hi/lo out ----------
__global__ __launch_bounds__(256) void agg128_kernel(const unsigned short* __restrict__ X,
                                                     const int* __restrict__ esrc,
                                                     const int* __restrict__ rowptr,
                                                     const float* __restrict__ dinv,
                                                     unsigned short* __restrict__ Ah,
                                                     unsigned short* __restrict__ Al) {
    int node = rfl(blockIdx.x * 4 + (threadIdx.x >> 6));
    int lane = threadIdx.x & 63;
    float ddst = dinv[node];
    int s = rfl(rowptr[node]);
    int e = rfl(rowptr[node + 1]);

    ushort2 h0 = *((const ushort2*)(X + (size_t)node * 128) + lane);
    float2 acc = make_float2(bf2f(h0.x), bf2f(h0.y));

    int j = s;
    for (; j + 8 <= e; j += 8) {
        int si[8];
#pragma unroll
        for (int u = 0; u < 8; u++) si[u] = rfl(esrc[j + u]);
        ushort2 xv[8];
#pragma unroll
        for (int u = 0; u < 8; u++)
            xv[u] = *((const ushort2*)(X + (size_t)si[u] * 128) + lane);
#pragma unroll
        for (int u = 0; u < 8; u++) {
            acc.x += bf2f(xv[u].x);
            acc.y += bf2f(xv[u].y);
        }
    }
    for (; j + 4 <= e; j += 4) {
        int si[4];
#pragma unroll
        for (int u = 0; u < 4; u++) si[u] = rfl(esrc[j + u]);
        ushort2 xv[4];
#pragma unroll
        for (int u = 0; u < 4; u++)
            xv[u] = *((const ushort2*)(X + (size_t)si[u] * 128) + lane);
#pragma unroll
        for (int u = 0; u < 4; u++) {
            acc.x += bf2f(xv[u].x);
            acc.y += bf2f(xv[u].y);
        }
    }
    for (; j < e; j++) {
        int src = rfl(esrc[j]);
        ushort2 xv = *((const ushort2*)(X + (size_t)src * 128) + lane);
        acc.x += bf2f(xv.x);
        acc.y += bf2f(xv.y);
    }
    acc.x *= ddst;
    acc.y *= ddst;
    size_t o = (size_t)node * 128 + lane * 2;
    ushort2 hi, lo;
    hi.x = f2bf(acc.x); lo.x = f2bf(acc.x - bf2f(hi.x));
    hi.y = f2bf(acc.y); lo.y = f2bf(acc.y - bf2f(hi.y));
    *(ushort2*)(Ah + o) = hi;
    *(ushort2*)(Al + o) = lo;
}

// ---------------- gather agg 256-dim from prescaled bf16, hi out ----------
__global__ __launch_bounds__(256) void agg256_kernel(const unsigned short* __restrict__ H,
                                                     const int* __restrict__ esrc,
                                                     const int* __restrict__ rowptr,
                                                     const float* __restrict__ dinv,
                                                     unsigned short* __restrict__ Ah) {
    int node = rfl(blockIdx.x * 4 + (threadIdx.x >> 6));
    int lane = threadIdx.x & 63;
    float ddst = dinv[node];
    int s = rfl(rowptr[node]);
    int e = rfl(rowptr[node + 1]);

    ushort4 h0 = *((const ushort4*)(H + (size_t)node * 256) + lane);
    float4 acc = make_float4(bf2f(h0.x), bf2f(h0.y), bf2f(h0.z), bf2f(h0.w));

    int j = s;
    for (; j + 8 <= e; j += 8) {
        int si[8];
#pragma unroll
        for (int u = 0; u < 8; u++) si[u] = rfl(esrc[j + u]);
        ushort4 xv[8];
#pragma unroll
        for (int u = 0; u < 8; u++)
            xv[u] = *((const ushort4*)(H + (size_t)si[u] * 256) + lane);
#pragma unroll
        for (int u = 0; u < 8; u++) {
            acc.x += bf2f(xv[u].x);
            acc.y += bf2f(xv[u].y);
            acc.z += bf2f(xv[u].z);
            acc.w += bf2f(xv[u].w);
        }
    }
    for (; j + 4 <= e; j += 4) {
        int si[4];
#pragma unroll
        for (int u = 0; u < 4; u++) si[u] = rfl(esrc[j + u]);
        ushort4 xv[4];
#pragma unroll
        for (int u = 0; u < 4; u++)
            xv[u] = *((const ushort4*)(H + (size_t)si[u] * 256) + lane);
#pragma unroll
        for (int u = 0; u < 4; u++) {
            acc.x += bf2f(xv[u].x);
            acc.y += bf2f(xv[u].y);
            acc.z += bf2f(xv[u].z);
            acc.w += bf2f(xv[u].w);
        }
    }
    for (; j < e; j++) {
        int src = rfl(esrc[j]);
        ushort4 xv = *((const ushort4*)(H + (size_t)src * 256) + lane);
        acc.x += bf2f(xv.x);
        acc.y += bf2f(xv.y);
        acc.z += bf2f(xv.z);
        acc.w += bf2f(xv.w);
    }
    acc.x *= ddst; acc.y *= ddst; acc.z *= ddst; acc.w *= ddst;
    size_t o = (size_t)node * 256 + lane * 4;
    ushort4 hi;
    hi.x = f2bf(acc.x); hi.y = f2bf(acc.y);
    hi.z = f2bf(acc.z); hi.w = f2bf(acc.w);
    *(ushort4*)(Ah + o) = hi;
}

// ---------------- MFMA GEMM: relu(A @ W + b) -> bf16 out OR fused mean-pool ----
// ASPLIT: A hi+lo (3-term) else hi only (2-term). SCALEOUT: row-scale output.
// POOL: r11/r12 post-mortem: keeping acc live across a RUNTIME epilogue loop
// spilled acc[4][4] to scratch (VGPR_Count 72, k-loop serialized, 177us).
// Fix: drain acc to a [128][129] f32 LDS tile with fully STATIC indices (acc
// dead immediately), then pool from LDS: thread t owns col t&127 / row-half
// (t>>7)*64, serial run-accumulate, one global f32 atomicAdd per graph
// boundary (~1.3K atomics/block; poolsum is L2-resident).
template <int K, bool ASPLIT, bool SCALEOUT, bool POOL>
__launch_bounds__(256, 2)
__global__ void mfma_gemm_bias_relu(const unsigned short* __restrict__ Ah,
                                    const unsigned short* __restrict__ Al,
                                    const unsigned short* __restrict__ Bh,
                                    const unsigned short* __restrict__ Bl,
                                    const float* __restrict__ bias,
                                    const float* __restrict__ dscale,
                                    const int* __restrict__ batch,
                                    float* __restrict__ poolsum,
                                    unsigned short* __restrict__ Cout) {
    constexpr int NT = ASPLIT ? 4 : 3;
    constexpr int STAGE_BYTES = NT * 8192;
    constexpr int POOLT_BYTES = 128 * 129 * 4;  // 66048, row-pad kills bank aliasing
    constexpr int LDS_BYTES = (POOL && POOLT_BYTES > STAGE_BYTES) ? POOLT_BYTES : STAGE_BYTES;
    __shared__ __align__(16) unsigned char ldsb[LDS_BYTES];
    unsigned short* lds = (unsigned short*)ldsb;
    unsigned short* Ahs = lds;
    unsigned short* Als = lds + 4096;                    // only valid if ASPLIT
    unsigned short* Bhs = lds + (ASPLIT ? 8192 : 4096);
    unsigned short* Bls = lds + (ASPLIT ? 12288 : 8192);
    __shared__ int sbatch[128];

    int tid = threadIdx.x;
    int bm = (blockIdx.y * 8 + (blockIdx.x & 7)) * 128;
    int bn = (blockIdx.x >> 3) * 128;
    int wid = tid >> 6, lane = tid & 63;
    int wm = wid & 1, wn = wid >> 1;
    int lrow = lane & 15, quad = lane >> 4;

    if (POOL && tid < 128) {
        int row = bm + tid;
        sbatch[tid] = (row < N_NODES) ? batch[row] : -1;
    }

    f32x4 acc[4][4];
#pragma unroll
    for (int mi = 0; mi < 4; mi++)
#pragma unroll
        for (int ni = 0; ni < 4; ni++) acc[mi][ni] = (f32x4){0.f, 0.f, 0.f, 0.f};

    for (int k0 = 0; k0 < K; k0 += 32) {
#pragma unroll
        for (int i = 0; i < NT * 2; i++) {
            int c = tid + 256 * i;
            int tile = c >> 9;
            int w = c & 511;
            int row = w >> 2;
            int part = w & 3;
            const unsigned short* g;
            if (ASPLIT) {
                if (tile == 0)      g = Ah + (size_t)(bm + row) * K + k0 + part * 8;
                else if (tile == 1) g = Al + (size_t)(bm + row) * K + k0 + part * 8;
                else if (tile == 2) g = Bh + (size_t)(bn + row) * K + k0 + part * 8;
                else                g = Bl + (size_t)(bn + row) * K + k0 + part * 8;
            } else {
                if (tile == 0)      g = Ah + (size_t)(bm + row) * K + k0 + part * 8;
                else if (tile == 1) g = Bh + (size_t)(bn + row) * K + k0 + part * 8;
                else                g = Bl + (size_t)(bn + row) * K + k0 + part * 8;
            }
            __builtin_amdgcn_global_load_lds(
                (gvoid_t*)g,
                (svoid_t*)((char*)lds + (size_t)c * 16),
                16, 0, 0);
        }
        __syncthreads();

        bf16x8 ah[4], al[4], bh[4], bl[4];
#pragma unroll
        for (int mi = 0; mi < 4; mi++) {
            int r = wm * 64 + mi * 16 + lrow;
            ah[mi] = *(const bf16x8*)&Ahs[r * 32 + quad * 8];
            if (ASPLIT) al[mi] = *(const bf16x8*)&Als[r * 32 + quad * 8];
        }
#pragma unroll
        for (int ni = 0; ni < 4; ni++) {
            int r = wn * 64 + ni * 16 + lrow;
            bh[ni] = *(const bf16x8*)&Bhs[r * 32 + quad * 8];
            bl[ni] = *(const bf16x8*)&Bls[r * 32 + quad * 8];
        }
#pragma unroll
        for (int mi = 0; mi < 4; mi++)
#pragma unroll
            for (int ni = 0; ni < 4; ni++) {
                acc[mi][ni] = __builtin_amdgcn_mfma_f32_16x16x32_bf16(ah[mi], bh[ni], acc[mi][ni], 0, 0, 0);
                acc[mi][ni] = __builtin_amdgcn_mfma_f32_16x16x32_bf16(ah[mi], bl[ni], acc[mi][ni], 0, 0, 0);
                if (ASPLIT)
                    acc[mi][ni] = __builtin_amdgcn_mfma_f32_16x16x32_bf16(al[mi], bh[ni], acc[mi][ni], 0, 0, 0);
            }
        __syncthreads();
    }

    float bv[4];
#pragma unroll
    for (int ni = 0; ni < 4; ni++) bv[ni] = bias[bn + wn * 64 + ni * 16 + lrow];

    if (POOL) {
        if (bm >= N_NODES) return;  // fully-pad row tile
        float* pool_lds = (float*)ldsb;

        // ---- phase 1: STATIC drain of acc -> LDS (acc dead after this) ----
#pragma unroll
        for (int mi = 0; mi < 4; mi++) {
            int prow = wm * 64 + mi * 16 + quad * 4;
#pragma unroll
            for (int ni = 0; ni < 4; ni++) {
                int pcol = wn * 64 + ni * 16 + lrow;
#pragma unroll
                for (int rr = 0; rr < 4; rr++) {
                    pool_lds[(prow + rr) * 129 + pcol] = fmaxf(acc[mi][ni][rr] + bv[ni], 0.f);
                }
            }
        }
        __syncthreads();

        // ---- phase 2: per-column run-accumulate over sorted rows ----
        int col = tid & 127;
        int r0 = (tid >> 7) * 64;
        int curg = sbatch[r0];
        float run = 0.f;
#pragma unroll 4
        for (int r = r0; r < r0 + 64; r++) {
            int g = sbatch[r];
            if (g != curg) {
                if (curg >= 0)
                    atomicAdd(&poolsum[(size_t)curg * 256 + bn + col], run);
                run = 0.f;
                curg = g;
            }
            run += pool_lds[r * 129 + col];
        }
        if (curg >= 0)
            atomicAdd(&poolsum[(size_t)curg * 256 + bn + col], run);
        return;
    }

    // ---- standard epilogue: bias + relu (+ row scale) + bf16 store ----
#pragma unroll
    for (int mi = 0; mi < 4; mi++) {
        int row0 = bm + wm * 64 + mi * 16 + quad * 4;
        float dsc[4];
        if (SCALEOUT) {
#pragma unroll
            for (int r = 0; r < 4; r++)
                dsc[r] = (row0 + r < N_NODES) ? dscale[row0 + r] : 0.f;
        }
#pragma unroll
        for (int ni = 0; ni < 4; ni++) {
            int col = bn + wn * 64 + ni * 16 + lrow;
#pragma unroll
            for (int r = 0; r < 4; r++) {
                int row = row0 + r;
                if (row < N_NODES) {
                    float v = fmaxf(acc[mi][ni][r] + bv[ni], 0.f);
                    if (SCALEOUT) v *= dsc[r];
                    Cout[(size_t)row * 256 + col] = f2bf(v);
                }
            }
        }
    }
}

// ---------------- MLP head on pooled sums ----------
__global__ __launch_bounds__(256) void mlp_kernel(const float* __restrict__ poolsum,
                                                  const int* __restrict__ batch,
                                                  const float* __restrict__ Wf1,
                                                  const float* __restrict__ bf1,
                                                  const float* __restrict__ Wf2,
                                                  const float* __restrict__ bf2,
                                                  float* __restrict__ out) {
    int g = blockIdx.x;
    int t = threadIdx.x;  // 0..255
    __shared__ int bounds[2];
    if (t < 2) {
        int target = g + t;
        int lo = 0, hi = N_NODES;
        while (lo < hi) {
            int mid = (lo + hi) >> 1;
            if (batch[mid] < target) lo = mid + 1;
            else hi = mid;
        }
        bounds[t] = lo;
    }
    __syncthreads();
    int lo = bounds[0], hi = bounds[1];
    float inv = (hi > lo) ? 1.0f / (float)(hi - lo) : 0.f;

    __shared__ float p[256];
    p[t] = poolsum[(size_t)g * 256 + t] * inv;
    __syncthreads();

    float hv = 0.f;
    if (t < 128) {
        float a = bf1[t];
#pragma unroll 8
        for (int k = 0; k < 256; k++) a = fmaf(p[k], Wf1[k * 128 + t], a);
        hv = fmaxf(a, 0.f) * Wf2[t];
    }
#pragma unroll
    for (int off = 32; off > 0; off >>= 1) hv += __shfl_down(hv, off, 64);
    __shared__ float partial[4];
    if ((t & 63) == 0) partial[t >> 6] = hv;
    __syncthreads();
    if (t == 0) out[g] = partial[0] + partial[1] + bf2[0];
}

extern "C" void kernel_launch(void* const* d_in, const int* in_sizes, int n_in,
                              void* d_out, int out_size, void* d_ws, size_t ws_size,
                              hipStream_t stream) {
    const float* x   = (const float*)d_in[0];
    const int*   ei  = (const int*)d_in[1];
    const int*   bat = (const int*)d_in[2];
    const float* W1  = (const float*)d_in[3];
    const float* b1  = (const float*)d_in[4];
    const float* W2  = (const float*)d_in[5];
    const float* b2  = (const float*)d_in[6];
    const float* Wf1 = (const float*)d_in[7];
    const float* bf1 = (const float*)d_in[8];
    const float* Wf2 = (const float*)d_in[9];
    const float* bf2 = (const float*)d_in[10];
    float* out = (float*)d_out;

    char* ws = (char*)d_ws;
    // layout (peak end 0x9B20000 = 162.5 MB):
    //   0x0000000 deg        0x0080000 dinv      0x0100000 rowptr
    //   0x01F0000 bsum
    //   0x0200000 esrc (6.4 MB)
    //   0x0820000 W1th  0x0830000 W1tl  0x0840000 W2th  0x0860000 W2tl
    //   0x0880000 A1h (25.6 MB) / later A2 (51.2 MB, single; ends ~0x3962000)
    //   0x20F0000 eord (6.4 MB, dead after fill) -> A1l (25.6 MB)  [A2 overlaps]
    //   0x4000000 poolsum (2 MB, in the hole before xbf)
    //   0x6A40000 xbf (25.6 MB) -> H1bf (51.2 MB) time-multiplexed (no H2 anymore)
    int*   deg    = (int*)(ws);
    float* dinv   = (float*)(ws + 0x0080000);
    int*   rowptr = (int*)(ws + 0x0100000);
    int*   bsum   = (int*)(ws + 0x01F0000);
    int*   esrc   = (int*)(ws + 0x0200000);
    unsigned short* W1th = (unsigned short*)(ws + 0x0820000);
    unsigned short* W1tl = (unsigned short*)(ws + 0x0830000);
    unsigned short* W2th = (unsigned short*)(ws + 0x0840000);
    unsigned short* W2tl = (unsigned short*)(ws + 0x0860000);
    unsigned short* A1h  = (unsigned short*)(ws + 0x0880000);
    int*   eord   = (int*)(ws + 0x20F0000);                    // dead before A1l written
    unsigned short* A1l  = (unsigned short*)(ws + 0x20F0000);
    unsigned short* A2   = (unsigned short*)(ws + 0x0880000);  // reuses A1h+A1l space
    float* poolsum = (float*)(ws + 0x4000000);
    unsigned short* xbf  = (unsigned short*)(ws + 0x6A40000);
    unsigned short* H1bf = (unsigned short*)(ws + 0x6A40000);  // overwrites dead xbf
    (void)ws_size;

    hipMemsetAsync(deg, 0, (size_t)N_NODES * sizeof(int), stream);
    hipMemsetAsync(poolsum, 0, (size_t)NUM_GRAPHS * HID * sizeof(float), stream);

    // CSR build front half (produces dinv needed by the prescaled prep)
    count_deg_kernel<<<(N_EDGES + 255) / 256, 256, 0, stream>>>(ei, deg, eord);
    blocksum_kernel<<<SCAN_BLOCKS, 1024, 0, stream>>>(deg, bsum, dinv);

    // merged prep (x prescale+cast, weight transpose+split)
    prep_kernel<<<X2BF_BLOCKS + 384, 256, 0, stream>>>(x, dinv, xbf, W1, W2,
                                                       W1th, W1tl, W2th, W2tl);

    // CSR build back half
    scanout_kernel<<<SCAN_BLOCKS, 1024, 0, stream>>>(deg, bsum, rowptr);
    fill_kernel<<<FILL_BLOCKS, 256, 0, stream>>>(ei, rowptr, eord, esrc);

    // layer 1: A1 = split(ddst * sum X'); H1' = dinv * relu(A1 @ W1 + b1)  [3-term]
    agg128_kernel<<<N_NODES / 4, 256, 0, stream>>>(xbf, esrc, rowptr, dinv, A1h, A1l);
    {
        dim3 grid(16, 98);
        mfma_gemm_bias_relu<IN_DIM, true, true, false><<<grid, 256, 0, stream>>>(
            A1h, A1l, W1th, W1tl, b1, dinv, nullptr, nullptr, H1bf);
    }

    // layer 2: A2 = bf16(ddst * sum H1'); poolsum += relu(A2 @ W2 + b2) per graph
    agg256_kernel<<<N_NODES / 4, 256, 0, stream>>>(H1bf, esrc, rowptr, dinv, A2);
    {
        dim3 grid(16, 98);
        mfma_gemm_bias_relu<HID, false, false, true><<<grid, 256, 0, stream>>>(
            A2, nullptr, W2th, W2tl, b2, nullptr, bat, poolsum, nullptr);
    }

    // MLP head on pooled sums
    mlp_kernel<<<NUM_GRAPHS, 256, 0, stream>>>(poolsum, bat, Wf1, bf1, Wf2, bf2, out);
}